// Round 5
// baseline (309.697 us; speedup 1.0000x reference)
//
#include <hip/hip_runtime.h>

// Problem constants (from reference): E=1024, H=16, D=64, B=32, S=1024.
// ALGEBRA: softmax over a length-1 key axis == 1.0 exactly, so attention
// collapses: attn_out[b,:] = Wo @ (Wv @ (W_heat @ heat[b] + b_heat) + bv) + bo
// (independent of s; the img projection / Q / K path is dead code).
// Final: out[b,s,:] = LayerNorm(img_feat[b,s,:] + a[b,:]) * gamma + beta.
// All tensors fp32. Vanilla HIP types / plain loads only.
//
// Round-4 post-mortem: FUSED row-LN plateaus at ~3.3 TB/s effective (the
// per-row shfl butterfly sits between the loads and the stores), while
// copy-shaped kernels on this chip do 6.3 TB/s (m13) and the harness fill
// 6.7 TB/s. So LN is split: a read-only stats pass (streams img+a, writes
// 8 B/row) + a copy-shaped apply pass (img re-read is L3-hot from the
// stats pass; bounded by the 128 MiB write).

#define E_DIM 1024
#define B_DIM 32
#define S_DIM 1024

// ---- GEMV stage: y[b,e] = dot(W[e,:], x[b,:]) + bias[e] -------------------
// (unchanged from the passing round-3 version)
__global__ __launch_bounds__(256) void gemv_xlds(
        const float* __restrict__ W,    // [E,E] row-major
        const float* __restrict__ bias, // [E]
        const float* __restrict__ x,    // [B,E]
        float* __restrict__ y) {        // [B,E]
    __shared__ float4 xs[8 * 256];       // 8 batches x 1024 f32 = 32 KiB
    const int t = threadIdx.x;
    const int rg = blockIdx.x & 255;     // row group -> rows [rg*4, rg*4+4)
    const int bq = blockIdx.x >> 8;      // batch quarter -> batches [bq*8, ..+8)

    const float4* x4 = reinterpret_cast<const float4*>(x) + (size_t)bq * 8 * 256;
    #pragma unroll
    for (int i = 0; i < 8; ++i)
        xs[i * 256 + t] = x4[i * 256 + t];
    __syncthreads();

    const int wave = t >> 6;
    const int lane = t & 63;
    const int e = rg * 4 + wave;

    const float4* w4 = reinterpret_cast<const float4*>(W + (size_t)e * E_DIM);
    float4 w0 = w4[lane];
    float4 w1 = w4[64 + lane];
    float4 w2 = w4[128 + lane];
    float4 w3 = w4[192 + lane];

    float acc[8];
    #pragma unroll
    for (int i = 0; i < 8; ++i) acc[i] = 0.f;

    #pragma unroll
    for (int i = 0; i < 8; ++i) {
        float4 a0 = xs[i * 256 + lane];
        float4 a1 = xs[i * 256 + 64 + lane];
        float4 a2 = xs[i * 256 + 128 + lane];
        float4 a3 = xs[i * 256 + 192 + lane];
        float r = w0.x * a0.x + w0.y * a0.y + w0.z * a0.z + w0.w * a0.w;
        r += w1.x * a1.x + w1.y * a1.y + w1.z * a1.z + w1.w * a1.w;
        r += w2.x * a2.x + w2.y * a2.y + w2.z * a2.z + w2.w * a2.w;
        r += w3.x * a3.x + w3.y * a3.y + w3.z * a3.z + w3.w * a3.w;
        acc[i] = r;
    }

    #pragma unroll
    for (int off = 32; off; off >>= 1) {
        #pragma unroll
        for (int i = 0; i < 8; ++i)
            acc[i] += __shfl_xor(acc[i], off, 64);
    }

    if (lane == 0) {
        const float bs = bias[e];
        #pragma unroll
        for (int i = 0; i < 8; ++i)
            y[(size_t)(bq * 8 + i) * E_DIM + e] = acc[i] + bs;
    }
}

// ---- LN pass 1: per-row mu/rstd of (img + a) -------------------------------
// One wave per row, 8 rows/wave, 3-buffer load pipeline (2 rows in flight).
// Read-only stream (stores are 8 B/row) -> should run at read BW (~6 TB/s).
__global__ __launch_bounds__(256) void ln_stats(
        const float* __restrict__ img,   // [B,S,E]
        const float* __restrict__ a,     // [B,E]
        float2* __restrict__ stats) {    // [B*S] {mu, rstd}
    const int t = threadIdx.x;
    const int wave = t >> 6;
    const int lane = t & 63;
    const int row0 = blockIdx.x * 32 + wave * 8;   // 32 rows/block, 8/wave
    const int b = row0 >> 10;                      // 32 | 1024: no straddle

    const float4* a4 = reinterpret_cast<const float4*>(a + (size_t)b * E_DIM);
    float4 av[4];
    #pragma unroll
    for (int p = 0; p < 4; ++p) av[p] = a4[p * 64 + lane];

    float4 xA[4], xB[4], xC[4];

#define LN_LOAD(X, rr)                                                        \
    {                                                                         \
        const float4* i4 =                                                    \
            reinterpret_cast<const float4*>(img + (size_t)(row0 + (rr)) * E_DIM); \
        X[0] = i4[lane];                                                      \
        X[1] = i4[64 + lane];                                                 \
        X[2] = i4[128 + lane];                                                \
        X[3] = i4[192 + lane];                                                \
    }

#define LN_STAT(X, rr)                                                        \
    {                                                                         \
        float s = 0.f, q = 0.f;                                               \
        _Pragma("unroll")                                                     \
        for (int p = 0; p < 4; ++p) {                                         \
            float yx = X[p].x + av[p].x;                                      \
            float yy = X[p].y + av[p].y;                                      \
            float yz = X[p].z + av[p].z;                                      \
            float yw = X[p].w + av[p].w;                                      \
            s += yx + yy + yz + yw;                                           \
            q += yx * yx + yy * yy + yz * yz + yw * yw;                       \
        }                                                                     \
        _Pragma("unroll")                                                     \
        for (int off = 32; off; off >>= 1) {                                  \
            s += __shfl_xor(s, off, 64);                                      \
            q += __shfl_xor(q, off, 64);                                      \
        }                                                                     \
        if (lane == 0) {                                                      \
            const float mu = s * (1.0f / E_DIM);                              \
            float2 st;                                                        \
            st.x = mu;                                                        \
            st.y = rsqrtf(q * (1.0f / E_DIM) - mu * mu + 1e-5f);              \
            stats[row0 + (rr)] = st;                                          \
        }                                                                     \
    }

    LN_LOAD(xA, 0)
    LN_LOAD(xB, 1)
    LN_LOAD(xC, 2) LN_STAT(xA, 0)
    LN_LOAD(xA, 3) LN_STAT(xB, 1)
    LN_LOAD(xB, 4) LN_STAT(xC, 2)
    LN_LOAD(xC, 5) LN_STAT(xA, 3)
    LN_LOAD(xA, 6) LN_STAT(xB, 4)
    LN_LOAD(xB, 7) LN_STAT(xC, 5)
    LN_STAT(xA, 6)
    LN_STAT(xB, 7)

#undef LN_LOAD
#undef LN_STAT
}

// ---- LN pass 2: copy-shaped apply ------------------------------------------
// Pure grid-stride elementwise: out = (img + a - mu) * rstd * gamma + beta.
// a/gamma/beta/stats are L1/L2-resident (tiny); img re-read is L3-hot from
// pass 1; the 128 MiB store bounds the kernel. No cross-lane ops at all.
__global__ __launch_bounds__(256) void ln_apply(
        const float* __restrict__ img,   // [B,S,E]
        const float* __restrict__ a,     // [B,E]
        const float* __restrict__ gamma, // [E]
        const float* __restrict__ beta,  // [E]
        const float2* __restrict__ stats,// [B*S]
        float* __restrict__ out) {       // [B,S,E]
    const int tid = blockIdx.x * 256 + threadIdx.x;   // 2048*256 = 524288 thr
    const float4* img4 = reinterpret_cast<const float4*>(img);
    const float4* a4   = reinterpret_cast<const float4*>(a);
    const float4* g4   = reinterpret_cast<const float4*>(gamma);
    const float4* b4   = reinterpret_cast<const float4*>(beta);
    float4* out4 = reinterpret_cast<float4*>(out);

    // total f4 elements: B*S*E/4 = 8388608; 16 per thread, stride 524288.
    #pragma unroll 4
    for (int k = 0; k < 16; ++k) {
        const int i = tid + k * 524288;
        const int row = i >> 8;           // 256 f4 per row
        const int e4 = i & 255;
        const int b = row >> 10;

        float4 iv = img4[i];
        float4 av = a4[b * 256 + e4];
        float2 st = stats[row];           // wave-uniform (64 f4 < 256/row)
        float4 gv = g4[e4];
        float4 bv = b4[e4];

        float4 ov;
        ov.x = (iv.x + av.x - st.x) * st.y * gv.x + bv.x;
        ov.y = (iv.y + av.y - st.x) * st.y * gv.y + bv.y;
        ov.z = (iv.z + av.z - st.x) * st.y * gv.z + bv.z;
        ov.w = (iv.w + av.w - st.x) * st.y * gv.w + bv.w;
        out4[i] = ov;
    }
}

extern "C" void kernel_launch(void* const* d_in, const int* in_sizes, int n_in,
                              void* d_out, int out_size, void* d_ws, size_t ws_size,
                              hipStream_t stream) {
    // setup_inputs order:
    // 0 img_feat [B,S,E], 1 heat_feat [B,E], 2 W_img, 3 b_img, 4 W_heat, 5 b_heat,
    // 6 Wq, 7 bq, 8 Wk, 9 bk, 10 Wv, 11 bv, 12 Wo, 13 bo, 14 gamma, 15 beta
    const float* heat   = (const float*)d_in[1];
    const float* W_heat = (const float*)d_in[4];
    const float* b_heat = (const float*)d_in[5];
    const float* Wv     = (const float*)d_in[10];
    const float* bvv    = (const float*)d_in[11];
    const float* Wo     = (const float*)d_in[12];
    const float* bo     = (const float*)d_in[13];
    const float* img    = (const float*)d_in[0];
    const float* gamma  = (const float*)d_in[14];
    const float* beta   = (const float*)d_in[15];
    float* out = (float*)d_out;

    // Workspace: 3 fp32 [B,E] buffers (384 KiB) + [B*S] float2 stats (256 KiB).
    float* ws = (float*)d_ws;
    float* tt = ws;                      // W_heat stage
    float* vv = ws + B_DIM * E_DIM;      // Wv stage
    float* aa = ws + 2 * B_DIM * E_DIM;  // Wo stage (attn_out rows)
    float2* st = (float2*)(ws + 3 * B_DIM * E_DIM);

    // 1024 blocks = 256 row-groups x 4 batch-quarters.
    gemv_xlds<<<1024, 256, 0, stream>>>(W_heat, b_heat, heat, tt);
    gemv_xlds<<<1024, 256, 0, stream>>>(Wv, bvv, tt, vv);
    gemv_xlds<<<1024, 256, 0, stream>>>(Wo, bo, vv, aa);

    // LN pass 1: 1024 blocks x 256 thr (32 rows/block, 8/wave, pipelined).
    ln_stats<<<(B_DIM * S_DIM) / 32, 256, 0, stream>>>(img, aa, st);
    // LN pass 2: copy-shaped, 2048 blocks x 256 thr, 16 f4 per thread.
    ln_apply<<<2048, 256, 0, stream>>>(img, aa, gamma, beta, st, out);
}

// Round 6
// 291.678 us; speedup vs baseline: 1.0618x; 1.0618x over previous
//
#include <hip/hip_runtime.h>

// Problem constants (from reference): E=1024, H=16, D=64, B=32, S=1024.
// ALGEBRA: softmax over a length-1 key axis == 1.0 exactly, so attention
// collapses: attn_out[b,:] = Wo @ (Wv @ (W_heat @ heat[b] + b_heat) + bv) + bo
// (independent of s; the img projection / Q / K path is dead code).
// Final: out[b,s,:] = LayerNorm(img_feat[b,s,:] + a[b,:]) * gamma + beta.
// All tensors fp32. Vanilla HIP types / plain loads only (nontemporal
// builtins correlated 2/2 with infra failures; never reintroduced).
//
// Round-5 post-mortem: split stats+apply REGRESSED (309.7 vs 289.9) -> the
// copy-shaped apply pass did NOT reach copy BW; L3-reuse bet failed. Revert
// to fused LN. Round-4's 3-buffer pipeline gained only ~6 us because the
// loads were pure program-order -- the scheduler is free to sink them to
// their uses, recreating the serial load->reduce->store chain. This round
// pins the schedule with __builtin_amdgcn_sched_barrier(0) after each load
// group (zero-instruction fence) and deepens to 3 rows in flight.

#define E_DIM 1024
#define B_DIM 32
#define S_DIM 1024

// ---- GEMV stage: y[b,e] = dot(W[e,:], x[b,:]) + bias[e] -------------------
// (unchanged from the passing round-3/4/5 version)
__global__ __launch_bounds__(256) void gemv_xlds(
        const float* __restrict__ W,    // [E,E] row-major
        const float* __restrict__ bias, // [E]
        const float* __restrict__ x,    // [B,E]
        float* __restrict__ y) {        // [B,E]
    __shared__ float4 xs[8 * 256];       // 8 batches x 1024 f32 = 32 KiB
    const int t = threadIdx.x;
    const int rg = blockIdx.x & 255;     // row group -> rows [rg*4, rg*4+4)
    const int bq = blockIdx.x >> 8;      // batch quarter -> batches [bq*8, ..+8)

    const float4* x4 = reinterpret_cast<const float4*>(x) + (size_t)bq * 8 * 256;
    #pragma unroll
    for (int i = 0; i < 8; ++i)
        xs[i * 256 + t] = x4[i * 256 + t];
    __syncthreads();

    const int wave = t >> 6;
    const int lane = t & 63;
    const int e = rg * 4 + wave;

    const float4* w4 = reinterpret_cast<const float4*>(W + (size_t)e * E_DIM);
    float4 w0 = w4[lane];
    float4 w1 = w4[64 + lane];
    float4 w2 = w4[128 + lane];
    float4 w3 = w4[192 + lane];

    float acc[8];
    #pragma unroll
    for (int i = 0; i < 8; ++i) acc[i] = 0.f;

    #pragma unroll
    for (int i = 0; i < 8; ++i) {
        float4 a0 = xs[i * 256 + lane];
        float4 a1 = xs[i * 256 + 64 + lane];
        float4 a2 = xs[i * 256 + 128 + lane];
        float4 a3 = xs[i * 256 + 192 + lane];
        float r = w0.x * a0.x + w0.y * a0.y + w0.z * a0.z + w0.w * a0.w;
        r += w1.x * a1.x + w1.y * a1.y + w1.z * a1.z + w1.w * a1.w;
        r += w2.x * a2.x + w2.y * a2.y + w2.z * a2.z + w2.w * a2.w;
        r += w3.x * a3.x + w3.y * a3.y + w3.z * a3.z + w3.w * a3.w;
        acc[i] = r;
    }

    #pragma unroll
    for (int off = 32; off; off >>= 1) {
        #pragma unroll
        for (int i = 0; i < 8; ++i)
            acc[i] += __shfl_xor(acc[i], off, 64);
    }

    if (lane == 0) {
        const float bs = bias[e];
        #pragma unroll
        for (int i = 0; i < 8; ++i)
            y[(size_t)(bq * 8 + i) * E_DIM + e] = acc[i] + bs;
    }
}

// ---- Fused residual-add + LayerNorm, ENFORCED software pipeline -----------
// One wave per row, 8 rows/wave, 4-buffer rotation = 3 rows (12 KiB) in
// flight per wave. sched_barrier(0) after each load group forbids the
// scheduler from sinking loads to their uses (the round-4 failure mode);
// each PROC then waits on a counted vmcnt(12), never vmcnt(0).
__global__ __launch_bounds__(256) void resid_ln(
        const float* __restrict__ img,   // [B,S,E]
        const float* __restrict__ a,     // [B,E]
        const float* __restrict__ gamma, // [E]
        const float* __restrict__ beta,  // [E]
        float* __restrict__ out) {       // [B,S,E]
    const int t = threadIdx.x;
    const int wave = t >> 6;
    const int lane = t & 63;
    const int row0 = blockIdx.x * 32 + wave * 8;   // 32 rows/block, 8/wave
    const int b = row0 >> 10;                      // 32 | 1024: no straddle

    const float4* g4  = reinterpret_cast<const float4*>(gamma);
    const float4* be4 = reinterpret_cast<const float4*>(beta);
    const float4* a4  = reinterpret_cast<const float4*>(a + (size_t)b * E_DIM);
    float4 gv[4], bv[4], av[4];
    #pragma unroll
    for (int p = 0; p < 4; ++p) {
        gv[p] = g4[p * 64 + lane];
        bv[p] = be4[p * 64 + lane];
        av[p] = a4[p * 64 + lane];
    }

    float4 xA[4], xB[4], xC[4], xD[4];

#define LN_LOAD(X, rr)                                                        \
    {                                                                         \
        const float4* i4 =                                                    \
            reinterpret_cast<const float4*>(img + (size_t)(row0 + (rr)) * E_DIM); \
        X[0] = i4[lane];                                                      \
        X[1] = i4[64 + lane];                                                 \
        X[2] = i4[128 + lane];                                                \
        X[3] = i4[192 + lane];                                                \
    }

#define LN_FENCE __builtin_amdgcn_sched_barrier(0);

#define LN_PROC(X, rr)                                                        \
    {                                                                         \
        float4 y[4];                                                          \
        float s = 0.f, q = 0.f;                                               \
        _Pragma("unroll")                                                     \
        for (int p = 0; p < 4; ++p) {                                         \
            y[p].x = X[p].x + av[p].x;                                        \
            y[p].y = X[p].y + av[p].y;                                        \
            y[p].z = X[p].z + av[p].z;                                        \
            y[p].w = X[p].w + av[p].w;                                        \
            s += y[p].x + y[p].y + y[p].z + y[p].w;                           \
            q += y[p].x * y[p].x + y[p].y * y[p].y                            \
               + y[p].z * y[p].z + y[p].w * y[p].w;                           \
        }                                                                     \
        _Pragma("unroll")                                                     \
        for (int off = 32; off; off >>= 1) {                                  \
            s += __shfl_xor(s, off, 64);                                      \
            q += __shfl_xor(q, off, 64);                                      \
        }                                                                     \
        const float mu   = s * (1.0f / E_DIM);                                \
        const float rstd = rsqrtf(q * (1.0f / E_DIM) - mu * mu + 1e-5f);      \
        float4* o4 =                                                          \
            reinterpret_cast<float4*>(out + (size_t)(row0 + (rr)) * E_DIM);   \
        _Pragma("unroll")                                                     \
        for (int p = 0; p < 4; ++p) {                                         \
            float4 ov;                                                        \
            ov.x = (y[p].x - mu) * rstd * gv[p].x + bv[p].x;                  \
            ov.y = (y[p].y - mu) * rstd * gv[p].y + bv[p].y;                  \
            ov.z = (y[p].z - mu) * rstd * gv[p].z + bv[p].z;                  \
            ov.w = (y[p].w - mu) * rstd * gv[p].w + bv[p].w;                  \
            o4[p * 64 + lane] = ov;                                           \
        }                                                                     \
    }

    // Enforced schedule: 3 rows of loads always in flight ahead of the
    // reduction being executed. Fences pin the load groups in place.
    LN_LOAD(xA, 0) LN_FENCE
    LN_LOAD(xB, 1) LN_FENCE
    LN_LOAD(xC, 2) LN_FENCE
    LN_LOAD(xD, 3) LN_FENCE
    LN_PROC(xA, 0)
    LN_LOAD(xA, 4) LN_FENCE
    LN_PROC(xB, 1)
    LN_LOAD(xB, 5) LN_FENCE
    LN_PROC(xC, 2)
    LN_LOAD(xC, 6) LN_FENCE
    LN_PROC(xD, 3)
    LN_LOAD(xD, 7) LN_FENCE
    LN_PROC(xA, 4)
    LN_PROC(xB, 5)
    LN_PROC(xC, 6)
    LN_PROC(xD, 7)

#undef LN_LOAD
#undef LN_FENCE
#undef LN_PROC
}

extern "C" void kernel_launch(void* const* d_in, const int* in_sizes, int n_in,
                              void* d_out, int out_size, void* d_ws, size_t ws_size,
                              hipStream_t stream) {
    // setup_inputs order:
    // 0 img_feat [B,S,E], 1 heat_feat [B,E], 2 W_img, 3 b_img, 4 W_heat, 5 b_heat,
    // 6 Wq, 7 bq, 8 Wk, 9 bk, 10 Wv, 11 bv, 12 Wo, 13 bo, 14 gamma, 15 beta
    const float* heat   = (const float*)d_in[1];
    const float* W_heat = (const float*)d_in[4];
    const float* b_heat = (const float*)d_in[5];
    const float* Wv     = (const float*)d_in[10];
    const float* bvv    = (const float*)d_in[11];
    const float* Wo     = (const float*)d_in[12];
    const float* bo     = (const float*)d_in[13];
    const float* img    = (const float*)d_in[0];
    const float* gamma  = (const float*)d_in[14];
    const float* beta   = (const float*)d_in[15];
    float* out = (float*)d_out;

    // Workspace: 3 fp32 [B,E] buffers = 384 KiB.
    float* ws = (float*)d_ws;
    float* tt = ws;                      // W_heat stage
    float* vv = ws + B_DIM * E_DIM;      // Wv stage
    float* aa = ws + 2 * B_DIM * E_DIM;  // Wo stage (attn_out rows)

    // 1024 blocks = 256 row-groups x 4 batch-quarters.
    gemv_xlds<<<1024, 256, 0, stream>>>(W_heat, b_heat, heat, tt);
    gemv_xlds<<<1024, 256, 0, stream>>>(Wv, bvv, tt, vv);
    gemv_xlds<<<1024, 256, 0, stream>>>(Wo, bo, vv, aa);

    // 1024 blocks x 256 thr; 32 rows/block (8 rows/wave, enforced pipeline).
    resid_ln<<<(B_DIM * S_DIM) / 32, 256, 0, stream>>>(img, aa, gamma, beta, out);
}